// Round 2
// baseline (885.661 us; speedup 1.0000x reference)
//
#include <hip/hip_runtime.h>
#include <math.h>

#define NATOM 2048
#define CD 128
#define SD 2
#define HN 8
#define DHD 16
#define CPD 16
#define TT 512
#define CTD 384
#define NBI 3
#define MR 4096  // SD*NATOM

__device__ __forceinline__ float sigm(float x){ return 1.0f/(1.0f+expf(-x)); }

// ---- workspace layout (float offsets) ----
#define OFF_W3    0ll        // 6 * 128*384  packed [gate|shift|og] per (iter, aln/t)
#define OFF_B3    294912ll   // 6 * 384
#define OFF_WQKVG 297216ll   // 3 * 128*512  [q|k|v|gate]
#define OFF_BQ    493824ll   // 3 * 512
#define OFF_WOUT  495360ll   // 3 * 128*128
#define OFF_WAB   544512ll   // 3 * 128*512  [t_a|t_b]
#define OFF_WTOUT 741120ll   // 3 * 256*128
#define OFF_WTOK  839424ll   // 128*384
#define OFF_SN    888576ll   // 6 * 2048*128
#define OFF_SNP   2461440ll  // 6 * 2048*384
#define OFF_A     7180032ll  // 4096*128
#define OFF_A1    7704320ll  // 4096*128
#define OFF_QKVG  8228608ll  // 4096*512
#define OFF_O     10325760ll // 4096*128
#define OFF_HID   10850048ll // 4096*256
#define OFF_ZB    11898624ll // 2048*128*8
#define OFF_QTOK  13995776ll // 4096*384
// total ~15.6M floats ~62.3 MB

struct WPtrs {
  const float *aln_gate_w, *aln_gate_b, *aln_shift_w, *og_w, *og_b;
  const float *t_aln_gate_w, *t_aln_gate_b, *t_aln_shift_w, *t_og_w, *t_og_b;
  const float *q_w, *q_b, *k_w, *v_w, *gate_w, *out_w;
  const float *t_a_w, *t_b_w, *t_out_w, *tok_w;
};

__global__ __launch_bounds__(256) void pack_kernel(WPtrs P, float* __restrict__ ws)
{
  long long idx = (long long)blockIdx.x*256 + threadIdx.x;
  const long long s0=294912, s1=2304, s2=196608, s3=1536, s4=49152, s5=196608, s6=98304, s7=49152;
  if (idx < s0) {
    int which = (int)(idx/49152); int r = (int)(idx%49152); int k=r/384, col=r%384;
    int i = which>>1, t = which&1;
    const float* src;
    if (col<128)      src = (t?P.t_aln_gate_w :P.aln_gate_w ) + i*16384 + k*128 + col;
    else if (col<256) src = (t?P.t_aln_shift_w:P.aln_shift_w) + i*16384 + k*128 + (col-128);
    else              src = (t?P.t_og_w       :P.og_w       ) + i*16384 + k*128 + (col-256);
    ws[OFF_W3+idx] = *src; return;
  }
  idx -= s0;
  if (idx < s1) {
    int which = (int)(idx/384); int col = (int)(idx%384); int i=which>>1, t=which&1;
    float v = 0.f;
    if (col<128)       v = (t?P.t_aln_gate_b:P.aln_gate_b)[i*128+col];
    else if (col>=256) v = (t?P.t_og_b      :P.og_b      )[i*128+col-256];
    ws[OFF_B3+idx] = v; return;
  }
  idx -= s1;
  if (idx < s2) {
    int i = (int)(idx/65536); int r = (int)(idx%65536); int k=r/512, col=r%512;
    int seg = col>>7, c = col&127;
    const float* src = (seg==0?P.q_w: seg==1?P.k_w: seg==2?P.v_w: P.gate_w) + i*16384 + k*128 + c;
    ws[OFF_WQKVG+idx] = *src; return;
  }
  idx -= s2;
  if (idx < s3) {
    int i = (int)(idx/512); int col = (int)(idx%512);
    ws[OFF_BQ+idx] = (col<128) ? P.q_b[i*128+col] : 0.f; return;
  }
  idx -= s3;
  if (idx < s4) { ws[OFF_WOUT+idx] = P.out_w[idx]; return; }
  idx -= s4;
  if (idx < s5) {
    int i = (int)(idx/65536); int r = (int)(idx%65536); int k=r/512, col=r%512;
    const float* src = (col<256) ? P.t_a_w + i*32768 + k*256 + col
                                 : P.t_b_w + i*32768 + k*256 + (col-256);
    ws[OFF_WAB+idx] = *src; return;
  }
  idx -= s5;
  if (idx < s6) { ws[OFF_WTOUT+idx] = P.t_out_w[idx]; return; }
  idx -= s6;
  if (idx < s7) { ws[OFF_WTOK+idx] = P.tok_w[idx]; return; }
}

__device__ __forceinline__ void wave_red2(float& a, float& b){
  #pragma unroll
  for (int m=32; m>=1; m>>=1){ a += __shfl_xor(a,m,64); b += __shfl_xor(b,m,64); }
}

// sn_all[which][n][c] = LN(atom_proj[n], w_which, b_which),  which = iter*2 + (0:aln,1:t_aln)
__global__ __launch_bounds__(64) void sn_kernel(const float* __restrict__ atom_proj,
  const float* __restrict__ aw, const float* __restrict__ ab,
  const float* __restrict__ tw, const float* __restrict__ tb, float* __restrict__ sn_all)
{
  int n = blockIdx.x, which = blockIdx.y;
  int i = which>>1, t = which&1;
  int c0 = threadIdx.x*2;
  float x0 = atom_proj[n*128+c0], x1 = atom_proj[n*128+c0+1];
  float s = x0+x1, sq = x0*x0+x1*x1;
  wave_red2(s,sq);
  float mu = s*(1.f/128.f), var = sq*(1.f/128.f) - mu*mu;
  float rs = rsqrtf(var + 1e-5f);
  const float* w = (t?tw:aw) + i*128;
  const float* b = (t?tb:ab) + i*128;
  long long base = (long long)which*262144 + n*128;
  sn_all[base+c0]   = (x0-mu)*rs*w[c0]   + b[c0];
  sn_all[base+c0+1] = (x1-mu)*rs*w[c0+1] + b[c0+1];
}

// out[m][c] = sigmoid(snp[n][c]) * ln_na(a[m])[c] + snp[n][128+c]
__global__ __launch_bounds__(64) void modln_kernel(const float* __restrict__ a,
    const float* __restrict__ snp, float* __restrict__ out)
{
  int m = blockIdx.x;
  int n = m & (NATOM-1);
  int c0 = threadIdx.x*2;
  float x0 = a[m*128+c0], x1 = a[m*128+c0+1];
  float s = x0+x1, sq = x0*x0+x1*x1;
  wave_red2(s,sq);
  float mu = s*(1.f/128.f), var = sq*(1.f/128.f) - mu*mu;
  float rs = rsqrtf(var + 1e-5f);
  const float* sp = snp + (long long)n*384;
  out[m*128+c0]   = sigm(sp[c0])  *((x0-mu)*rs) + sp[128+c0];
  out[m*128+c0+1] = sigm(sp[c0+1])*((x1-mu)*rs) + sp[128+c0+1];
}

__global__ __launch_bounds__(256) void copy_f(const float* __restrict__ src, float* __restrict__ dst, int n){
  int i = blockIdx.x*256 + threadIdx.x;
  if (i<n) dst[i] = src[i];
}

__global__ __launch_bounds__(256) void gateo_kernel(const float* __restrict__ qkvg,
    const float* __restrict__ o, float* __restrict__ og){
  int idx = blockIdx.x*256 + threadIdx.x;
  if (idx < MR*CD){
    int m = idx>>7, c = idx&127;
    og[idx] = sigm(qkvg[(long long)m*512 + 384 + c]) * o[idx];
  }
}

__global__ __launch_bounds__(256) void silu_kernel(const float* __restrict__ hp, float* __restrict__ hid){
  int idx = blockIdx.x*256 + threadIdx.x;
  if (idx < MR*256){
    int m = idx>>8, c = idx&255;
    float x = hp[(long long)m*512 + c];
    hid[idx] = x*sigm(x) * hp[(long long)m*512 + 256 + c];
  }
}

// zb[q][j][h], j in [0,128), key m = (q/32)*32 - 48 + j (0 if out of range)
__global__ __launch_bounds__(256) void zb_kernel(const float* __restrict__ atom_pair,
  const float* __restrict__ plw, const float* __restrict__ plb, const float* __restrict__ pw,
  float* __restrict__ zb, int it)
{
  int idx = blockIdx.x*256 + threadIdx.x;
  if (idx >= NATOM*128) return;
  int q = idx>>7, j = idx&127;
  int m = (q & ~31) - 48 + j;
  float out[8] = {0,0,0,0,0,0,0,0};
  if (m>=0 && m<NATOM){
    float x[16]; float s=0.f, sq=0.f;
    const float* p = atom_pair + ((long long)q*NATOM + m)*16;
    #pragma unroll
    for (int c=0;c<16;c++){ x[c]=p[c]; s+=x[c]; sq+=x[c]*x[c]; }
    float mu = s*(1.f/16.f), var = sq*(1.f/16.f)-mu*mu, rs = rsqrtf(var+1e-5f);
    #pragma unroll
    for (int c=0;c<16;c++){
      float xn = (x[c]-mu)*rs*plw[it*16+c] + plb[it*16+c];
      #pragma unroll
      for (int h=0;h<8;h++) out[h] += xn * pw[it*128 + c*8 + h];
    }
  }
  float4* zp = (float4*)&zb[(long long)idx*8];
  zp[0] = make_float4(out[0],out[1],out[2],out[3]);
  zp[1] = make_float4(out[4],out[5],out[6],out[7]);
}

// banded attention: grid (qblock=64, h=8, s=2), block 256
__global__ __launch_bounds__(256) void attn_kernel(const float* __restrict__ qkvg,
  const float* __restrict__ zb, const float* __restrict__ mask, float* __restrict__ o)
{
  int qb = blockIdx.x, h = blockIdx.y, s = blockIdx.z;
  int wlo = qb*32-48; if (wlo<0) wlo=0;
  int whi = qb*32+80; if (whi>NATOM) whi=NATOM;
  int W = whi-wlo;
  int jbase = wlo - (qb*32-48);
  __shared__ float Q[32][16], Kx[128][16], V[128][16], L[32][128], red[32][8], rowv[32];
  int tid = threadIdx.x;
  for (int idx=tid; idx<32*16; idx+=256){
    int r=idx>>4, d=idx&15;
    Q[r][d] = qkvg[((long long)(s*NATOM + qb*32 + r))*512 + h*16 + d];
  }
  for (int idx=tid; idx<W*16; idx+=256){
    int j=idx>>4, d=idx&15; int m=wlo+j;
    long long row = ((long long)(s*NATOM + m))*512;
    Kx[j][d] = qkvg[row + 128 + h*16 + d];
    V[j][d]  = qkvg[row + 256 + h*16 + d];
  }
  __syncthreads();
  for (int idx=tid; idx<32*128; idx+=256){
    int r=idx>>7, j=idx&127;
    float l = -1e30f;
    if (j<W){
      int m = wlo+j;
      float dot = 0.f;
      #pragma unroll
      for (int d=0;d<16;d++) dot += Q[r][d]*Kx[j][d];
      l = dot*0.25f
        + zb[((long long)(qb*32+r)*128 + (j+jbase))*8 + h]
        + (mask[m]-1.0f)*1e8f;
    }
    L[r][j] = l;
  }
  __syncthreads();
  int r = tid>>3, g = tid&7;
  float pmax = -1e30f;
  for (int j=g*16; j<g*16+16; j++) pmax = fmaxf(pmax, L[r][j]);
  red[r][g] = pmax; __syncthreads();
  if (g==0){ float mx=red[r][0]; for(int u=1;u<8;u++) mx=fmaxf(mx,red[r][u]); rowv[r]=mx; }
  __syncthreads();
  float mx = rowv[r];
  float psum = 0.f;
  for (int j=g*16; j<g*16+16; j++){ float e = expf(L[r][j]-mx); L[r][j]=e; psum += e; }
  red[r][g] = psum; __syncthreads();
  if (g==0){ float sm=0.f; for(int u=0;u<8;u++) sm+=red[r][u]; rowv[r]=sm; }
  __syncthreads();
  for (int idx=tid; idx<32*16; idx+=256){
    int q2=idx>>4, d=idx&15;
    float acc = 0.f;
    for (int j=0;j<W;j++) acc += L[q2][j]*V[j][d];
    o[((long long)(s*NATOM + qb*32 + q2))*128 + h*16 + d] = acc / rowv[q2];
  }
}

// generic tiled f32 GEMM: C = A(MxK) @ B(KxN) (+bias), modes: 0 store, 1 relu, 2 a += sigmoid(gate)*acc
__global__ __launch_bounds__(256) void gemm_k(
    const float* __restrict__ A, long long strideA,
    const float* __restrict__ B, long long strideB,
    const float* __restrict__ bias, long long strideBias,
    float* C, long long strideC,
    int M, int Nc, int K, int mode,
    const float* __restrict__ gate, int gate_ld, int gate_coloff)
{
  int z = blockIdx.z;
  A += z*strideA; B += z*strideB; C += z*strideC;
  if (bias) bias += z*strideBias;
  __shared__ float As[64][17];
  __shared__ float Bs[16][64];
  int tid = threadIdx.x;
  int tx = tid & 15, ty = tid >> 4;
  int rowBase = blockIdx.y*64, colBase = blockIdx.x*64;
  float acc[4][4] = {};
  for (int kt = 0; kt < K; kt += 16){
    int off = tid*4;
    int ar = off>>4, ak = off&15;
    float4 av = *(const float4*)(A + (long long)(rowBase+ar)*K + kt + ak);
    As[ar][ak]=av.x; As[ar][ak+1]=av.y; As[ar][ak+2]=av.z; As[ar][ak+3]=av.w;
    int br = off>>6, bc = off&63;
    float4 bv = *(const float4*)(B + (long long)(kt+br)*Nc + colBase + bc);
    Bs[br][bc]=bv.x; Bs[br][bc+1]=bv.y; Bs[br][bc+2]=bv.z; Bs[br][bc+3]=bv.w;
    __syncthreads();
    #pragma unroll
    for (int kk=0; kk<16; kk++){
      float af[4], bfv[4];
      #pragma unroll
      for (int i2=0;i2<4;i2++) af[i2] = As[ty*4+i2][kk];
      #pragma unroll
      for (int j=0;j<4;j++) bfv[j] = Bs[kk][tx*4+j];
      #pragma unroll
      for (int i2=0;i2<4;i2++)
        #pragma unroll
        for (int j=0;j<4;j++) acc[i2][j] = fmaf(af[i2], bfv[j], acc[i2][j]);
    }
    __syncthreads();
  }
  #pragma unroll
  for (int i2=0;i2<4;i2++){
    int R = rowBase + ty*4 + i2;
    #pragma unroll
    for (int j=0;j<4;j++){
      int Cc = colBase + tx*4 + j;
      float v = acc[i2][j];
      if (bias) v += bias[Cc];
      long long ci = (long long)R*Nc + Cc;
      if (mode==1) C[ci] = fmaxf(v, 0.f);
      else if (mode==2){
        int n = R & (NATOM-1);
        C[ci] += sigm(gate[(long long)n*gate_ld + gate_coloff + Cc]) * v;
      } else C[ci] = v;
    }
  }
}

__global__ __launch_bounds__(128) void tokagg_kernel(const int* __restrict__ tok_idx,
    const float* __restrict__ qtok, float* __restrict__ out)
{
  int t = blockIdx.x;
  int lo=0, hi=NATOM;
  while (lo<hi){ int mid=(lo+hi)>>1; if (tok_idx[mid] < t) lo=mid+1; else hi=mid; }
  int start = lo;
  lo = start; hi = NATOM;
  while (lo<hi){ int mid=(lo+hi)>>1; if (tok_idx[mid] <= t) lo=mid+1; else hi=mid; }
  int end = lo;
  int cnt = end - start;
  float inv = 1.0f / (float)(cnt>0 ? cnt : 1);
  for (int s=0; s<SD; s++)
    for (int c=threadIdx.x; c<CTD; c+=128){
      float acc = 0.f;
      for (int n=start; n<end; n++) acc += qtok[((long long)(s*NATOM+n))*CTD + c];
      out[(long long)(s*TT + t)*CTD + c] = acc*inv;
    }
}

extern "C" void kernel_launch(void* const* d_in, const int* in_sizes, int n_in,
                              void* d_out, int out_size, void* d_ws, size_t ws_size,
                              hipStream_t stream)
{
  const float* atom_single = (const float*)d_in[0];
  const float* atom_proj   = (const float*)d_in[1];
  const float* atom_pair   = (const float*)d_in[2];
  const float* mask        = (const float*)d_in[3];
  const int*   tok_idx     = (const int*)  d_in[4];
  const float* aln_s_w     = (const float*)d_in[5];
  const float* aln_s_b     = (const float*)d_in[6];
  const float* aln_gate_w  = (const float*)d_in[7];
  const float* aln_gate_b  = (const float*)d_in[8];
  const float* aln_shift_w = (const float*)d_in[9];
  const float* q_w         = (const float*)d_in[10];
  const float* q_b         = (const float*)d_in[11];
  const float* k_w         = (const float*)d_in[12];
  const float* v_w         = (const float*)d_in[13];
  const float* pair_ln_w   = (const float*)d_in[14];
  const float* pair_ln_b   = (const float*)d_in[15];
  const float* pair_w      = (const float*)d_in[16];
  const float* gate_w      = (const float*)d_in[17];
  const float* out_w       = (const float*)d_in[18];
  const float* og_w        = (const float*)d_in[19];
  const float* og_b        = (const float*)d_in[20];
  const float* t_aln_s_w   = (const float*)d_in[21];
  const float* t_aln_s_b   = (const float*)d_in[22];
  const float* t_aln_gate_w= (const float*)d_in[23];
  const float* t_aln_gate_b= (const float*)d_in[24];
  const float* t_aln_shift_w=(const float*)d_in[25];
  const float* t_a_w       = (const float*)d_in[26];
  const float* t_b_w       = (const float*)d_in[27];
  const float* t_out_w     = (const float*)d_in[28];
  const float* t_og_w      = (const float*)d_in[29];
  const float* t_og_b      = (const float*)d_in[30];
  const float* tok_w       = (const float*)d_in[31];

  float* ws = (float*)d_ws;

  WPtrs P;
  P.aln_gate_w=aln_gate_w; P.aln_gate_b=aln_gate_b; P.aln_shift_w=aln_shift_w;
  P.og_w=og_w; P.og_b=og_b;
  P.t_aln_gate_w=t_aln_gate_w; P.t_aln_gate_b=t_aln_gate_b; P.t_aln_shift_w=t_aln_shift_w;
  P.t_og_w=t_og_w; P.t_og_b=t_og_b;
  P.q_w=q_w; P.q_b=q_b; P.k_w=k_w; P.v_w=v_w; P.gate_w=gate_w; P.out_w=out_w;
  P.t_a_w=t_a_w; P.t_b_w=t_b_w; P.t_out_w=t_out_w; P.tok_w=tok_w;

  pack_kernel<<<3471,256,0,stream>>>(P, ws);
  sn_kernel<<<dim3(NATOM,6),64,0,stream>>>(atom_proj, aln_s_w, aln_s_b, t_aln_s_w, t_aln_s_b, ws+OFF_SN);
  // snp[which] = sn[which] @ W3[which] + b3[which]   (2048 x 384 x 128, z=6)
  gemm_k<<<dim3(6,32,6),256,0,stream>>>(ws+OFF_SN, 262144ll, ws+OFF_W3, 49152ll,
      ws+OFF_B3, 384ll, ws+OFF_SNP, 786432ll, NATOM, 384, 128, 0, nullptr, 0, 0);
  copy_f<<<2048,256,0,stream>>>(atom_single, ws+OFF_A, MR*CD);

  for (int i=0;i<NBI;i++){
    // a1 = sigmoid(gate_pre)*ln_na(a) + shift
    modln_kernel<<<MR,64,0,stream>>>(ws+OFF_A, ws+OFF_SNP + (long long)(2*i)*786432, ws+OFF_A1);
    // qkvg = a1 @ [q|k|v|gate] (+[q_b|0|0|0])
    gemm_k<<<dim3(8,64,1),256,0,stream>>>(ws+OFF_A1, 0, ws+OFF_WQKVG + (long long)i*65536, 0,
        ws+OFF_BQ + (long long)i*512, 0, ws+OFF_QKVG, 0, MR, 512, 128, 0, nullptr, 0, 0);
    // banded pair bias
    zb_kernel<<<1024,256,0,stream>>>(atom_pair, pair_ln_w, pair_ln_b, pair_w, ws+OFF_ZB, i);
    // attention
    attn_kernel<<<dim3(64,8,2),256,0,stream>>>(ws+OFF_QKVG, ws+OFF_ZB, mask, ws+OFF_O);
    // og = sigmoid(gate)*o
    gateo_kernel<<<2048,256,0,stream>>>(ws+OFF_QKVG, ws+OFF_O, ws+OFF_A1);
    // a += sigmoid(og_pre) * (og @ out_w)
    gemm_k<<<dim3(2,64,1),256,0,stream>>>(ws+OFF_A1, 0, ws+OFF_WOUT + (long long)i*16384, 0,
        nullptr, 0, ws+OFF_A, 0, MR, 128, 128, 2,
        ws+OFF_SNP + (long long)(2*i)*786432, 384, 256);
    // a2 = sigmoid(t_gate_pre)*ln_na(a) + t_shift
    modln_kernel<<<MR,64,0,stream>>>(ws+OFF_A, ws+OFF_SNP + (long long)(2*i+1)*786432, ws+OFF_A1);
    // hidden_pre = a2 @ [t_a|t_b]
    gemm_k<<<dim3(8,64,1),256,0,stream>>>(ws+OFF_A1, 0, ws+OFF_WAB + (long long)i*65536, 0,
        nullptr, 0, ws+OFF_QKVG, 0, MR, 512, 128, 0, nullptr, 0, 0);
    // hidden = silu(hp_a)*hp_b
    silu_kernel<<<4096,256,0,stream>>>(ws+OFF_QKVG, ws+OFF_HID);
    // a += sigmoid(t_og_pre) * (hidden @ t_out_w)
    gemm_k<<<dim3(2,64,1),256,0,stream>>>(ws+OFF_HID, 0, ws+OFF_WTOUT + (long long)i*32768, 0,
        nullptr, 0, ws+OFF_A, 0, MR, 128, 256, 2,
        ws+OFF_SNP + (long long)(2*i+1)*786432, 384, 256);
  }
  // q_tok = relu(a @ tok_w)
  gemm_k<<<dim3(6,64,1),256,0,stream>>>(ws+OFF_A, 0, ws+OFF_WTOK, 0, nullptr, 0,
      ws+OFF_QTOK, 0, MR, CTD, 128, 1, nullptr, 0, 0);
  // token scatter-mean
  tokagg_kernel<<<TT,128,0,stream>>>(tok_idx, ws+OFF_QTOK, (float*)d_out);
}

// Round 4
// 755.980 us; speedup vs baseline: 1.1715x; 1.1715x over previous
//
#include <hip/hip_runtime.h>
#include <math.h>

#define NATOM 2048
#define CD 128
#define SD 2
#define TT 512
#define CTD 384
#define NBI 3
#define MR 4096  // SD*NATOM

typedef unsigned short ushortx;
typedef __attribute__((ext_vector_type(8))) short bf16x8;
typedef __attribute__((ext_vector_type(4))) float f32x4;

__device__ __forceinline__ float sigm(float x){ return 1.0f/(1.0f+expf(-x)); }
__device__ __forceinline__ ushortx f2b(float f){
  union { float f; unsigned u; } v; v.f = f;
  unsigned r = v.u + 0x7fffu + ((v.u>>16)&1u);
  return (ushortx)(r>>16);
}

// ---- workspace layout (byte offsets, 256-aligned) ----
#define OFFB_W3T    0ll        // ushort 6*384*128   [n][k] transposed [gate|shift|og]
#define OFFB_B3     589824ll   // f32 6*384
#define OFFB_WQKVGT 599040ll   // ushort 3*512*128
#define OFFB_BQ     992256ll   // f32 3*512
#define OFFB_WOUTT  998400ll   // ushort 3*128*128
#define OFFB_WABT   1096704ll  // ushort 3*512*128
#define OFFB_WTOUTT 1489920ll  // ushort 3*128*256
#define OFFB_WTOKT  1686528ll  // ushort 384*128
#define OFFB_SN     1784832ll  // ushort 6*2048*128
#define OFFB_A1     4930560ll  // ushort 4096*128
#define OFFB_HID    5979136ll  // ushort 4096*256
#define OFFB_ABF    8076288ll  // ushort 4096*128
#define OFFB_SNP    9124864ll  // f32 6*2048*384
#define OFFB_A      27999232ll // f32 4096*128
#define OFFB_QKVG   30096384ll // f32 4096*512
#define OFFB_ZB     38484992ll // f32 3*2048*128*8
#define OFFB_QTOK   63650816ll // f32 4096*384

struct WPtrs {
  const float *aln_gate_w, *aln_gate_b, *aln_shift_w, *og_w, *og_b;
  const float *t_aln_gate_w, *t_aln_gate_b, *t_aln_shift_w, *t_og_w, *t_og_b;
  const float *q_w, *q_b, *k_w, *v_w, *gate_w, *out_w;
  const float *t_a_w, *t_b_w, *t_out_w, *tok_w;
};

__global__ __launch_bounds__(256) void pack_kernel(WPtrs P, char* __restrict__ wsb)
{
  long long idx = (long long)blockIdx.x*256 + threadIdx.x;
  const long long s0=294912, s1=2304, s2=196608, s3=1536, s4=49152, s5=196608, s6=98304, s7=49152;
  if (idx < s0) { // W3T[which][n][k] = W[i][k][col]
    int which = (int)(idx/49152); int r = (int)(idx%49152); int n=r/128, k=r%128;
    int i = which>>1, t = which&1;
    const float* src;
    if (n<128)      src = (t?P.t_aln_gate_w :P.aln_gate_w ) + i*16384 + k*128 + n;
    else if (n<256) src = (t?P.t_aln_shift_w:P.aln_shift_w) + i*16384 + k*128 + (n-128);
    else            src = (t?P.t_og_w       :P.og_w       ) + i*16384 + k*128 + (n-256);
    ((ushortx*)(wsb+OFFB_W3T))[idx] = f2b(*src); return;
  }
  idx -= s0;
  if (idx < s1) {
    int which = (int)(idx/384); int col = (int)(idx%384); int i=which>>1, t=which&1;
    float v = 0.f;
    if (col<128)       v = (t?P.t_aln_gate_b:P.aln_gate_b)[i*128+col];
    else if (col>=256) v = (t?P.t_og_b      :P.og_b      )[i*128+col-256];
    ((float*)(wsb+OFFB_B3))[idx] = v; return;
  }
  idx -= s1;
  if (idx < s2) { // WQKVGT[i][n][k]
    int i = (int)(idx/65536); int r = (int)(idx%65536); int n=r/128, k=r%128;
    int seg = n>>7, c = n&127;
    const float* src = (seg==0?P.q_w: seg==1?P.k_w: seg==2?P.v_w: P.gate_w) + i*16384 + k*128 + c;
    ((ushortx*)(wsb+OFFB_WQKVGT))[idx] = f2b(*src); return;
  }
  idx -= s2;
  if (idx < s3) {
    int i = (int)(idx/512); int col = (int)(idx%512);
    ((float*)(wsb+OFFB_BQ))[idx] = (col<128) ? P.q_b[i*128+col] : 0.f; return;
  }
  idx -= s3;
  if (idx < s4) { // WOUTT[i][n][k] = out_w[i][k][n]
    int i = (int)(idx/16384); int r = (int)(idx%16384); int n=r/128, k=r%128;
    ((ushortx*)(wsb+OFFB_WOUTT))[idx] = f2b(P.out_w[i*16384 + k*128 + n]); return;
  }
  idx -= s4;
  if (idx < s5) { // WABT[i][n][k]
    int i = (int)(idx/65536); int r = (int)(idx%65536); int n=r/128, k=r%128;
    const float* src = (n<256) ? P.t_a_w + i*32768 + k*256 + n
                               : P.t_b_w + i*32768 + k*256 + (n-256);
    ((ushortx*)(wsb+OFFB_WABT))[idx] = f2b(*src); return;
  }
  idx -= s5;
  if (idx < s6) { // WTOUTT[i][n][k], k in [0,256)
    int i = (int)(idx/32768); int r = (int)(idx%32768); int n=r/256, k=r%256;
    ((ushortx*)(wsb+OFFB_WTOUTT))[idx] = f2b(P.t_out_w[i*32768 + k*128 + n]); return;
  }
  idx -= s6;
  if (idx < s7) { // WTOKT[n][k] = tok_w[k][n]
    int n = (int)(idx/128); int k = (int)(idx%128);
    ((ushortx*)(wsb+OFFB_WTOKT))[idx] = f2b(P.tok_w[k*384 + n]); return;
  }
}

__device__ __forceinline__ void wave_red2(float& a, float& b){
  #pragma unroll
  for (int m=32; m>=1; m>>=1){ a += __shfl_xor(a,m,64); b += __shfl_xor(b,m,64); }
}

__global__ __launch_bounds__(64) void sn_kernel(const float* __restrict__ atom_proj,
  const float* __restrict__ aw, const float* __restrict__ ab,
  const float* __restrict__ tw, const float* __restrict__ tb, ushortx* __restrict__ sn_all)
{
  int n = blockIdx.x, which = blockIdx.y;
  int i = which>>1, t = which&1;
  int c0 = threadIdx.x*2;
  float x0 = atom_proj[n*128+c0], x1 = atom_proj[n*128+c0+1];
  float s = x0+x1, sq = x0*x0+x1*x1;
  wave_red2(s,sq);
  float mu = s*(1.f/128.f), var = sq*(1.f/128.f) - mu*mu;
  float rs = rsqrtf(var + 1e-5f);
  const float* w = (t?tw:aw) + i*128;
  const float* b = (t?tb:ab) + i*128;
  long long base = (long long)which*262144 + n*128;
  sn_all[base+c0]   = f2b((x0-mu)*rs*w[c0]   + b[c0]);
  sn_all[base+c0+1] = f2b((x1-mu)*rs*w[c0+1] + b[c0+1]);
}

// out(bf16)[m][c] = sigmoid(snp[n][c]) * ln_na(a[m])[c] + snp[n][128+c]
__global__ __launch_bounds__(64) void modln_kernel(const float* __restrict__ a,
    const float* __restrict__ snp, ushortx* __restrict__ out)
{
  int m = blockIdx.x;
  int n = m & (NATOM-1);
  int c0 = threadIdx.x*2;
  float x0 = a[m*128+c0], x1 = a[m*128+c0+1];
  float s = x0+x1, sq = x0*x0+x1*x1;
  wave_red2(s,sq);
  float mu = s*(1.f/128.f), var = sq*(1.f/128.f) - mu*mu;
  float rs = rsqrtf(var + 1e-5f);
  const float* sp = snp + (long long)n*384;
  out[m*128+c0]   = f2b(sigm(sp[c0])  *((x0-mu)*rs) + sp[128+c0]);
  out[m*128+c0+1] = f2b(sigm(sp[c0+1])*((x1-mu)*rs) + sp[128+c0+1]);
}

__global__ __launch_bounds__(256) void copy_f(const float* __restrict__ src, float* __restrict__ dst, int n){
  int i = blockIdx.x*256 + threadIdx.x;
  if (i<n) dst[i] = src[i];
}

__global__ __launch_bounds__(256) void castf2b_kernel(const float* __restrict__ src, ushortx* __restrict__ dst, int n){
  int i = blockIdx.x*256 + threadIdx.x;
  if (i<n) dst[i] = f2b(src[i]);
}

__global__ __launch_bounds__(256) void silu_kernel(const float* __restrict__ hp, ushortx* __restrict__ hid){
  int idx = blockIdx.x*256 + threadIdx.x;
  if (idx < MR*256){
    int m = idx>>8, c = idx&255;
    float x = hp[(long long)m*512 + c];
    hid[idx] = f2b(x*sigm(x) * hp[(long long)m*512 + 256 + c]);
  }
}

// zb_all[it][q][j][h] for all 3 iters; atom_pair read once
__global__ __launch_bounds__(256) void zb_kernel(const float* __restrict__ atom_pair,
  const float* __restrict__ plw, const float* __restrict__ plb, const float* __restrict__ pw,
  float* __restrict__ zb)
{
  int idx = blockIdx.x*256 + threadIdx.x;
  if (idx >= NATOM*128) return;
  int q = idx>>7, j = idx&127;
  int m = (q & ~31) - 48 + j;
  bool ok = (m>=0 && m<NATOM);
  float x[16]; float mu=0.f, rs=0.f;
  if (ok){
    float s=0.f, sq=0.f;
    const float* p = atom_pair + ((long long)q*NATOM + m)*16;
    #pragma unroll
    for (int c=0;c<16;c++){ x[c]=p[c]; s+=x[c]; sq+=x[c]*x[c]; }
    mu = s*(1.f/16.f); float var = sq*(1.f/16.f)-mu*mu; rs = rsqrtf(var+1e-5f);
  }
  for (int it=0; it<NBI; it++){
    float out[8] = {0,0,0,0,0,0,0,0};
    if (ok){
      #pragma unroll
      for (int c=0;c<16;c++){
        float xn = (x[c]-mu)*rs*plw[it*16+c] + plb[it*16+c];
        #pragma unroll
        for (int h=0;h<8;h++) out[h] += xn * pw[it*128 + c*8 + h];
      }
    }
    float4* zp = (float4*)&zb[(long long)it*2097152 + (long long)idx*8];
    zp[0] = make_float4(out[0],out[1],out[2],out[3]);
    zp[1] = make_float4(out[4],out[5],out[6],out[7]);
  }
}

// banded attention + fused output gate: writes og(bf16) = sigmoid(gate)*o
__global__ __launch_bounds__(256) void attn_kernel(const float* __restrict__ qkvg,
  const float* __restrict__ zb, const float* __restrict__ mask, ushortx* __restrict__ og)
{
  int qb = blockIdx.x, h = blockIdx.y, s = blockIdx.z;
  int wlo = qb*32-48; if (wlo<0) wlo=0;
  int whi = qb*32+80; if (whi>NATOM) whi=NATOM;
  int W = whi-wlo;
  int jbase = wlo - (qb*32-48);
  __shared__ float Q[32][16], Kx[128][16], V[128][16], L[32][128], red[32][8], rowv[32];
  int tid = threadIdx.x;
  for (int idx=tid; idx<32*16; idx+=256){
    int r=idx>>4, d=idx&15;
    Q[r][d] = qkvg[((long long)(s*NATOM + qb*32 + r))*512 + h*16 + d];
  }
  for (int idx=tid; idx<W*16; idx+=256){
    int j=idx>>4, d=idx&15; int m=wlo+j;
    long long row = ((long long)(s*NATOM + m))*512;
    Kx[j][d] = qkvg[row + 128 + h*16 + d];
    V[j][d]  = qkvg[row + 256 + h*16 + d];
  }
  __syncthreads();
  for (int idx=tid; idx<32*128; idx+=256){
    int r=idx>>7, j=idx&127;
    float l = -1e30f;
    if (j<W){
      int m = wlo+j;
      float dot = 0.f;
      #pragma unroll
      for (int d=0;d<16;d++) dot += Q[r][d]*Kx[j][d];
      l = dot*0.25f
        + zb[((long long)(qb*32+r)*128 + (j+jbase))*8 + h]
        + (mask[m]-1.0f)*1e8f;
    }
    L[r][j] = l;
  }
  __syncthreads();
  int r = tid>>3, g = tid&7;
  float pmax = -1e30f;
  for (int j=g*16; j<g*16+16; j++) pmax = fmaxf(pmax, L[r][j]);
  red[r][g] = pmax; __syncthreads();
  if (g==0){ float mx=red[r][0]; for(int u=1;u<8;u++) mx=fmaxf(mx,red[r][u]); rowv[r]=mx; }
  __syncthreads();
  float mx = rowv[r];
  float psum = 0.f;
  for (int j=g*16; j<g*16+16; j++){ float e = expf(L[r][j]-mx); L[r][j]=e; psum += e; }
  red[r][g] = psum; __syncthreads();
  if (g==0){ float sm=0.f; for(int u=0;u<8;u++) sm+=red[r][u]; rowv[r]=sm; }
  __syncthreads();
  for (int idx=tid; idx<32*16; idx+=256){
    int q2=idx>>4, d=idx&15;
    float acc = 0.f;
    for (int j=0;j<W;j++) acc += L[q2][j]*V[j][d];
    long long mrow = (long long)(s*NATOM + qb*32 + q2);
    float gt = qkvg[mrow*512 + 384 + h*16 + d];
    og[mrow*128 + h*16 + d] = f2b(sigm(gt) * (acc / rowv[q2]));
  }
}

// bf16 MFMA GEMM: C(MxN,f32) = A(MxK,bf16 row-major) @ B^T (B stored [N][K] bf16) (+bias)
// modes: 0 store, 1 relu, 2 C += sigmoid(gate[n][coloff+c])*acc
__global__ __launch_bounds__(256) void gemm_mfma(
    const ushortx* __restrict__ A, long long strideA,
    const ushortx* __restrict__ B, long long strideB,
    const float* __restrict__ bias, long long strideBias,
    float* C, long long strideC,
    int M, int N, int K, int mode,
    const float* __restrict__ gate, int gate_ld, int gate_coloff)
{
  int z = blockIdx.z;
  A += z*strideA; B += z*strideB; C += z*strideC;
  if (bias) bias += z*strideBias;
  __shared__ ushortx At[64][136];
  __shared__ ushortx Bt[64][136];
  int tid = threadIdx.x;
  int rowBase = blockIdx.y*64, colBase = blockIdx.x*64;
  int wave = tid>>6, lane = tid&63;
  int wr = (wave>>1)*32, wc = (wave&1)*32;
  int lr = lane&15, lk = (lane>>4)*8;
  f32x4 acc[2][2];
  #pragma unroll
  for (int i=0;i<2;i++)
    #pragma unroll
    for (int j=0;j<2;j++) acc[i][j] = (f32x4){0.f,0.f,0.f,0.f};

  int sr = tid>>2, sc = (tid&3)*32;
  for (int kc=0; kc<K; kc+=128){
    if (kc) __syncthreads();
    const float4* ag = (const float4*)(A + (long long)(rowBase+sr)*K + kc + sc);
    const float4* bg = (const float4*)(B + (long long)(colBase+sr)*K + kc + sc);
    #pragma unroll
    for (int u=0;u<4;u++){
      *(float4*)&At[sr][sc+u*8] = ag[u];
      *(float4*)&Bt[sr][sc+u*8] = bg[u];
    }
    __syncthreads();
    #pragma unroll
    for (int ks=0; ks<4; ks++){
      bf16x8 a0 = *(const bf16x8*)&At[wr+lr][ks*32+lk];
      bf16x8 a1 = *(const bf16x8*)&At[wr+16+lr][ks*32+lk];
      bf16x8 b0 = *(const bf16x8*)&Bt[wc+lr][ks*32+lk];
      bf16x8 b1 = *(const bf16x8*)&Bt[wc+16+lr][ks*32+lk];
      acc[0][0] = __builtin_amdgcn_mfma_f32_16x16x32_bf16(a0,b0,acc[0][0],0,0,0);
      acc[0][1] = __builtin_amdgcn_mfma_f32_16x16x32_bf16(a0,b1,acc[0][1],0,0,0);
      acc[1][0] = __builtin_amdgcn_mfma_f32_16x16x32_bf16(a1,b0,acc[1][0],0,0,0);
      acc[1][1] = __builtin_amdgcn_mfma_f32_16x16x32_bf16(a1,b1,acc[1][1],0,0,0);
    }
  }
  int crow0 = rowBase + wr + (lane>>4)*4;
  int ccol0 = colBase + wc + lr;
  #pragma unroll
  for (int i=0;i<2;i++){
    #pragma unroll
    for (int j=0;j<2;j++){
      int col = ccol0 + j*16;
      float bv = bias ? bias[col] : 0.f;
      #pragma unroll
      for (int rr=0; rr<4; rr++){
        int row = crow0 + i*16 + rr;
        float v = acc[i][j][rr] + bv;
        long long ci = (long long)row*N + col;
        if (mode==1) C[ci] = fmaxf(v, 0.f);
        else if (mode==2){
          int n = row & (NATOM-1);
          C[ci] += sigm(gate[(long long)n*gate_ld + gate_coloff + col]) * v;
        } else C[ci] = v;
      }
    }
  }
}

__global__ __launch_bounds__(128) void tokagg_kernel(const int* __restrict__ tok_idx,
    const float* __restrict__ qtok, float* __restrict__ out)
{
  int t = blockIdx.x;
  int lo=0, hi=NATOM;
  while (lo<hi){ int mid=(lo+hi)>>1; if (tok_idx[mid] < t) lo=mid+1; else hi=mid; }
  int start = lo;
  lo = start; hi = NATOM;
  while (lo<hi){ int mid=(lo+hi)>>1; if (tok_idx[mid] <= t) lo=mid+1; else hi=mid; }
  int end = lo;
  int cnt = end - start;
  float inv = 1.0f / (float)(cnt>0 ? cnt : 1);
  for (int s=0; s<SD; s++)
    for (int c=threadIdx.x; c<CTD; c+=128){
      float acc = 0.f;
      for (int n=start; n<end; n++) acc += qtok[((long long)(s*NATOM+n))*CTD + c];
      out[(long long)(s*TT + t)*CTD + c] = acc*inv;
    }
}

extern "C" void kernel_launch(void* const* d_in, const int* in_sizes, int n_in,
                              void* d_out, int out_size, void* d_ws, size_t ws_size,
                              hipStream_t stream)
{
  const float* atom_single = (const float*)d_in[0];
  const float* atom_proj   = (const float*)d_in[1];
  const float* atom_pair   = (const float*)d_in[2];
  const float* mask        = (const float*)d_in[3];
  const int*   tok_idx     = (const int*)  d_in[4];
  const float* aln_s_w     = (const float*)d_in[5];
  const float* aln_s_b     = (const float*)d_in[6];
  const float* pair_ln_w   = (const float*)d_in[14];
  const float* pair_ln_b   = (const float*)d_in[15];
  const float* pair_w      = (const float*)d_in[16];
  const float* t_aln_s_w   = (const float*)d_in[21];
  const float* t_aln_s_b   = (const float*)d_in[22];

  char* wsb = (char*)d_ws;
  ushortx* W3T    = (ushortx*)(wsb+OFFB_W3T);
  float*   B3     = (float*)  (wsb+OFFB_B3);
  ushortx* WQKVGT = (ushortx*)(wsb+OFFB_WQKVGT);
  float*   BQ     = (float*)  (wsb+OFFB_BQ);
  ushortx* WOUTT  = (ushortx*)(wsb+OFFB_WOUTT);
  ushortx* WABT   = (ushortx*)(wsb+OFFB_WABT);
  ushortx* WTOUTT = (ushortx*)(wsb+OFFB_WTOUTT);
  ushortx* WTOKT  = (ushortx*)(wsb+OFFB_WTOKT);
  ushortx* SN     = (ushortx*)(wsb+OFFB_SN);
  ushortx* A1     = (ushortx*)(wsb+OFFB_A1);
  ushortx* HID    = (ushortx*)(wsb+OFFB_HID);
  ushortx* ABF    = (ushortx*)(wsb+OFFB_ABF);
  float*   SNP    = (float*)  (wsb+OFFB_SNP);
  float*   Af     = (float*)  (wsb+OFFB_A);
  float*   QKVG   = (float*)  (wsb+OFFB_QKVG);
  float*   ZB     = (float*)  (wsb+OFFB_ZB);
  float*   QTOK   = (float*)  (wsb+OFFB_QTOK);

  WPtrs P;
  P.aln_gate_w=(const float*)d_in[7];  P.aln_gate_b=(const float*)d_in[8];  P.aln_shift_w=(const float*)d_in[9];
  P.og_w=(const float*)d_in[19]; P.og_b=(const float*)d_in[20];
  P.t_aln_gate_w=(const float*)d_in[23]; P.t_aln_gate_b=(const float*)d_in[24]; P.t_aln_shift_w=(const float*)d_in[25];
  P.t_og_w=(const float*)d_in[29]; P.t_og_b=(const float*)d_in[30];
  P.q_w=(const float*)d_in[10]; P.q_b=(const float*)d_in[11]; P.k_w=(const float*)d_in[12];
  P.v_w=(const float*)d_in[13]; P.gate_w=(const float*)d_in[17]; P.out_w=(const float*)d_in[18];
  P.t_a_w=(const float*)d_in[26]; P.t_b_w=(const float*)d_in[27]; P.t_out_w=(const float*)d_in[28];
  P.tok_w=(const float*)d_in[31];

  pack_kernel<<<3471,256,0,stream>>>(P, wsb);
  sn_kernel<<<dim3(NATOM,6),64,0,stream>>>(atom_proj, aln_s_w, aln_s_b, t_aln_s_w, t_aln_s_b, SN);
  zb_kernel<<<1024,256,0,stream>>>(atom_pair, pair_ln_w, pair_ln_b, pair_w, ZB);
  // snp[which] = sn[which] @ W3[which]^T + b3
  gemm_mfma<<<dim3(6,32,6),256,0,stream>>>(SN, 262144ll, W3T, 49152ll,
      B3, 384ll, SNP, 786432ll, NATOM, 384, 128, 0, nullptr, 0, 0);
  copy_f<<<2048,256,0,stream>>>(atom_single, Af, MR*CD);

  for (int i=0;i<NBI;i++){
    modln_kernel<<<MR,64,0,stream>>>(Af, SNP + (long long)(2*i)*786432, A1);
    gemm_mfma<<<dim3(8,64,1),256,0,stream>>>(A1, 0, WQKVGT + (long long)i*65536, 0,
        BQ + (long long)i*512, 0, QKVG, 0, MR, 512, 128, 0, nullptr, 0, 0);
    attn_kernel<<<dim3(64,8,2),256,0,stream>>>(QKVG, ZB + (long long)i*2097152, mask, A1);
    gemm_mfma<<<dim3(2,64,1),256,0,stream>>>(A1, 0, WOUTT + (long long)i*16384, 0,
        nullptr, 0, Af, 0, MR, 128, 128, 2,
        SNP + (long long)(2*i)*786432, 384, 256);
    modln_kernel<<<MR,64,0,stream>>>(Af, SNP + (long long)(2*i+1)*786432, A1);
    gemm_mfma<<<dim3(8,64,1),256,0,stream>>>(A1, 0, WABT + (long long)i*65536, 0,
        nullptr, 0, QKVG, 0, MR, 512, 128, 0, nullptr, 0, 0);
    silu_kernel<<<4096,256,0,stream>>>(QKVG, HID);
    gemm_mfma<<<dim3(2,64,1),256,0,stream>>>(HID, 0, WTOUTT + (long long)i*32768, 0,
        nullptr, 0, Af, 0, MR, 128, 256, 2,
        SNP + (long long)(2*i+1)*786432, 384, 256);
  }
  castf2b_kernel<<<2048,256,0,stream>>>(Af, ABF, MR*CD);
  gemm_mfma<<<dim3(6,64,1),256,0,stream>>>(ABF, 0, WTOKT, 0, nullptr, 0,
      QTOK, 0, MR, CTD, 128, 1, nullptr, 0, 0);
  tokagg_kernel<<<TT,128,0,stream>>>(tok_idx, QTOK, (float*)d_out);
}

// Round 5
// 636.046 us; speedup vs baseline: 1.3924x; 1.1886x over previous
//
#include <hip/hip_runtime.h>
#include <math.h>

#define NATOM 2048
#define CD 128
#define SD 2
#define TT 512
#define CTD 384
#define NBI 3
#define MR 4096  // SD*NATOM

typedef unsigned short ushortx;
typedef __attribute__((ext_vector_type(8))) short bf16x8;
typedef __attribute__((ext_vector_type(4))) float f32x4;

__device__ __forceinline__ float sigm(float x){ return 1.0f/(1.0f+expf(-x)); }
__device__ __forceinline__ ushortx f2b(float f){
  union { float f; unsigned u; } v; v.f = f;
  unsigned r = v.u + 0x7fffu + ((v.u>>16)&1u);
  return (ushortx)(r>>16);
}
union U8 { ushortx u[8]; float4 v; };

// ---- workspace layout (byte offsets, 256-aligned) ----
#define OFFB_W3T    0ll        // ushort 6*384*128   [n][k] [gate|shift|og]
#define OFFB_B3     589824ll   // f32 6*384
#define OFFB_WQKVGT 599040ll   // ushort 3*512*128
#define OFFB_BQ     992256ll   // f32 3*512
#define OFFB_WOUTT  998400ll   // ushort 3*128*128
#define OFFB_WABT   1096704ll  // ushort 3*512*128
#define OFFB_WTOUTT 1489920ll  // ushort 3*128*256
#define OFFB_WTOKT  1686528ll  // ushort 384*128
#define OFFB_A1     4930560ll  // ushort 4096*128 (attention og output)
#define OFFB_SNP    9124864ll  // f32 6*2048*384
#define OFFB_A      27999232ll // f32 4096*128
#define OFFB_QKVG   30096384ll // f32 4096*512
#define OFFB_ZB     38484992ll // f32 3*8*2048*128
#define OFFB_QTOK   63650816ll // f32 4096*384

struct WPtrs {
  const float *aln_gate_w, *aln_gate_b, *aln_shift_w, *og_w, *og_b;
  const float *t_aln_gate_w, *t_aln_gate_b, *t_aln_shift_w, *t_og_w, *t_og_b;
  const float *q_w, *q_b, *k_w, *v_w, *gate_w, *out_w;
  const float *t_a_w, *t_b_w, *t_out_w, *tok_w;
};

__global__ __launch_bounds__(256) void pack_kernel(WPtrs P, char* __restrict__ wsb)
{
  long long idx = (long long)blockIdx.x*256 + threadIdx.x;
  const long long s0=294912, s1=2304, s2=196608, s3=1536, s4=49152, s5=196608, s6=98304, s7=49152;
  if (idx < s0) { // W3T[which][n][k]
    int which = (int)(idx/49152); int r = (int)(idx%49152); int n=r/128, k=r%128;
    int i = which>>1, t = which&1;
    const float* src;
    if (n<128)      src = (t?P.t_aln_gate_w :P.aln_gate_w ) + i*16384 + k*128 + n;
    else if (n<256) src = (t?P.t_aln_shift_w:P.aln_shift_w) + i*16384 + k*128 + (n-128);
    else            src = (t?P.t_og_w       :P.og_w       ) + i*16384 + k*128 + (n-256);
    ((ushortx*)(wsb+OFFB_W3T))[idx] = f2b(*src); return;
  }
  idx -= s0;
  if (idx < s1) {
    int which = (int)(idx/384); int col = (int)(idx%384); int i=which>>1, t=which&1;
    float v = 0.f;
    if (col<128)       v = (t?P.t_aln_gate_b:P.aln_gate_b)[i*128+col];
    else if (col>=256) v = (t?P.t_og_b      :P.og_b      )[i*128+col-256];
    ((float*)(wsb+OFFB_B3))[idx] = v; return;
  }
  idx -= s1;
  if (idx < s2) { // WQKVGT[i][n][k]
    int i = (int)(idx/65536); int r = (int)(idx%65536); int n=r/128, k=r%128;
    int seg = n>>7, c = n&127;
    const float* src = (seg==0?P.q_w: seg==1?P.k_w: seg==2?P.v_w: P.gate_w) + i*16384 + k*128 + c;
    ((ushortx*)(wsb+OFFB_WQKVGT))[idx] = f2b(*src); return;
  }
  idx -= s2;
  if (idx < s3) {
    int i = (int)(idx/512); int col = (int)(idx%512);
    ((float*)(wsb+OFFB_BQ))[idx] = (col<128) ? P.q_b[i*128+col] : 0.f; return;
  }
  idx -= s3;
  if (idx < s4) { // WOUTT
    int i = (int)(idx/16384); int r = (int)(idx%16384); int n=r/128, k=r%128;
    ((ushortx*)(wsb+OFFB_WOUTT))[idx] = f2b(P.out_w[i*16384 + k*128 + n]); return;
  }
  idx -= s4;
  if (idx < s5) { // WABT
    int i = (int)(idx/65536); int r = (int)(idx%65536); int n=r/128, k=r%128;
    const float* src = (n<256) ? P.t_a_w + i*32768 + k*256 + n
                               : P.t_b_w + i*32768 + k*256 + (n-256);
    ((ushortx*)(wsb+OFFB_WABT))[idx] = f2b(*src); return;
  }
  idx -= s5;
  if (idx < s6) { // WTOUTT
    int i = (int)(idx/32768); int r = (int)(idx%32768); int n=r/256, k=r%256;
    ((ushortx*)(wsb+OFFB_WTOUTT))[idx] = f2b(P.t_out_w[i*32768 + k*128 + n]); return;
  }
  idx -= s6;
  if (idx < s7) { // WTOKT
    int n = (int)(idx/128); int k = (int)(idx%128);
    ((ushortx*)(wsb+OFFB_WTOKT))[idx] = f2b(P.tok_w[k*384 + n]); return;
  }
}

__global__ __launch_bounds__(256) void copy_f(const float* __restrict__ src, float* __restrict__ dst, int n){
  int i = blockIdx.x*256 + threadIdx.x;
  if (i<n) dst[i] = src[i];
}

// zb_all[it][h][q][j], j in [0,128): key m = (q&~31)-48+j
__global__ __launch_bounds__(256) void zb_kernel(const float* __restrict__ atom_pair,
  const float* __restrict__ plw, const float* __restrict__ plb, const float* __restrict__ pw,
  float* __restrict__ zb)
{
  int idx = blockIdx.x*256 + threadIdx.x;
  int q = idx>>7, j = idx&127;
  int m = (q & ~31) - 48 + j;
  bool ok = (m>=0 && m<NATOM);
  float x[16]; float mu=0.f, rs=0.f;
  if (ok){
    float s=0.f, sq=0.f;
    const float* p = atom_pair + ((long long)q*NATOM + m)*16;
    #pragma unroll
    for (int c=0;c<16;c++){ x[c]=p[c]; s+=x[c]; sq+=x[c]*x[c]; }
    mu = s*(1.f/16.f); float var = sq*(1.f/16.f)-mu*mu; rs = rsqrtf(var+1e-5f);
  }
  #pragma unroll
  for (int it=0; it<NBI; it++){
    float out[8] = {0,0,0,0,0,0,0,0};
    if (ok){
      #pragma unroll
      for (int c=0;c<16;c++){
        float xn = (x[c]-mu)*rs*plw[it*16+c] + plb[it*16+c];
        #pragma unroll
        for (int h=0;h<8;h++) out[h] += xn * pw[it*128 + c*8 + h];
      }
    }
    #pragma unroll
    for (int h=0;h<8;h++)
      zb[(((long long)it*8+h)*NATOM + q)*128 + j] = out[h];
  }
}

// banded attention + fused output gate; zb layout [h][q][j]
__global__ __launch_bounds__(256) void attn_kernel(const float* __restrict__ qkvg,
  const float* __restrict__ zb, const float* __restrict__ mask, ushortx* __restrict__ og)
{
  int qb = blockIdx.x, h = blockIdx.y, s = blockIdx.z;
  int base = qb*32 - 48;
  __shared__ float Qs[32][20], Ks[128][20], Vs[128][20], Ls[32][132], maskb[128];
  __shared__ float redx[32][8], rowv[32];
  int tid = threadIdx.x;
  for (int idx=tid; idx<32*4; idx+=256){
    int r=idx>>2, d4=(idx&3)*4;
    *(float4*)&Qs[r][d4] = *(const float4*)&qkvg[((long long)(s*NATOM + qb*32 + r))*512 + h*16 + d4];
  }
  for (int idx=tid; idx<128*4; idx+=256){
    int j=idx>>2, d4=(idx&3)*4;
    int m = base + j; int mc = m<0?0:(m>NATOM-1?NATOM-1:m);
    long long row = ((long long)(s*NATOM + mc))*512;
    *(float4*)&Ks[j][d4] = *(const float4*)&qkvg[row + 128 + h*16 + d4];
    *(float4*)&Vs[j][d4] = *(const float4*)&qkvg[row + 256 + h*16 + d4];
  }
  if (tid < 128){
    int m = base + tid;
    maskb[tid] = (m>=0 && m<NATOM) ? (mask[m]-1.0f)*1e8f : -1e30f;
  }
  __syncthreads();
  int r = tid>>3, g = tid&7;
  {
    float4 q0=*(float4*)&Qs[r][0], q1=*(float4*)&Qs[r][4], q2=*(float4*)&Qs[r][8], q3=*(float4*)&Qs[r][12];
    const float* zrow = zb + ((long long)h*NATOM + (qb*32+r))*128;
    #pragma unroll
    for (int j=g; j<128; j+=8){
      float4 k0=*(float4*)&Ks[j][0], k1=*(float4*)&Ks[j][4], k2=*(float4*)&Ks[j][8], k3=*(float4*)&Ks[j][12];
      float dot = q0.x*k0.x + q0.y*k0.y + q0.z*k0.z + q0.w*k0.w
                + q1.x*k1.x + q1.y*k1.y + q1.z*k1.z + q1.w*k1.w
                + q2.x*k2.x + q2.y*k2.y + q2.z*k2.z + q2.w*k2.w
                + q3.x*k3.x + q3.y*k3.y + q3.z*k3.z + q3.w*k3.w;
      Ls[r][j] = dot*0.25f + zrow[j] + maskb[j];
    }
  }
  __syncthreads();
  float pmax = -1e30f;
  for (int j=g*16; j<g*16+16; j++) pmax = fmaxf(pmax, Ls[r][j]);
  redx[r][g] = pmax; __syncthreads();
  if (g==0){ float mx=redx[r][0]; for(int u=1;u<8;u++) mx=fmaxf(mx,redx[r][u]); rowv[r]=mx; }
  __syncthreads();
  float mx = rowv[r];
  float psum = 0.f;
  for (int j=g*16; j<g*16+16; j++){ float e = expf(Ls[r][j]-mx); Ls[r][j]=e; psum += e; }
  redx[r][g] = psum; __syncthreads();
  if (g==0){ float sm=0.f; for(int u=0;u<8;u++) sm+=redx[r][u]; rowv[r]=sm; }
  __syncthreads();
  {
    int q2=tid>>3, dg=(tid>>1)&3, jh=tid&1;
    float4 acc = make_float4(0.f,0.f,0.f,0.f);
    for (int j=jh*64; j<jh*64+64; j++){
      float p = Ls[q2][j];
      float4 v = *(float4*)&Vs[j][dg*4];
      acc.x += p*v.x; acc.y += p*v.y; acc.z += p*v.z; acc.w += p*v.w;
    }
    acc.x += __shfl_xor(acc.x,1); acc.y += __shfl_xor(acc.y,1);
    acc.z += __shfl_xor(acc.z,1); acc.w += __shfl_xor(acc.w,1);
    if (jh==0){
      long long mrow = (long long)(s*NATOM + qb*32 + q2);
      float inv = 1.0f / rowv[q2];
      float4 gt = *(const float4*)&qkvg[mrow*512 + 384 + h*16 + dg*4];
      ushortx* op = og + mrow*128 + h*16 + dg*4;
      op[0] = f2b(sigm(gt.x)*acc.x*inv);
      op[1] = f2b(sigm(gt.y)*acc.y*inv);
      op[2] = f2b(sigm(gt.z)*acc.z*inv);
      op[3] = f2b(sigm(gt.w)*acc.w*inv);
    }
  }
}

// MFMA GEMM with fused A-staging.
// AM: 0 = A bf16 [M][K]; 1 = adaptive-LN of f32 A[M][128] with snp p1 (gate/shift);
//     2 = silu(hp[c])*hp[256+c] from f32 [M][512], K=256; 3 = f32->bf16 cast [M][128];
//     4 = LN(atom_proj)*w+b (w,b per z from p1..p4), M=2048.
// C-modes: 0 store, 1 relu, 2 C += sigmoid(gate[n][coloff+col])*acc
template<int AM>
__global__ __launch_bounds__(256) void gemm_f(
    const void* __restrict__ Asrc, long long strideA,
    const ushortx* __restrict__ B, long long strideB,
    const float* __restrict__ bias, long long strideBias,
    float* C, long long strideC,
    int M, int N, int K, int mode,
    const float* __restrict__ gate, int gate_ld, int gate_coloff,
    const float* __restrict__ p1, const float* __restrict__ p2,
    const float* __restrict__ p3, const float* __restrict__ p4)
{
  int z = blockIdx.z;
  B += z*strideB; C += z*strideC;
  if (bias) bias += z*strideBias;
  __shared__ ushortx At[64][136];
  __shared__ ushortx Bt[64][136];
  int tid = threadIdx.x;
  int rowBase = blockIdx.y*64, colBase = blockIdx.x*64;
  int wave = tid>>6, lane = tid&63;
  int wr = (wave>>1)*32, wc = (wave&1)*32;
  int lr = lane&15, lk = (lane>>4)*8;
  f32x4 acc[2][2];
  #pragma unroll
  for (int i=0;i<2;i++)
    #pragma unroll
    for (int j=0;j<2;j++) acc[i][j] = (f32x4){0.f,0.f,0.f,0.f};

  int sr = tid>>2, q = tid&3, cs = q*32;
  int row = rowBase + sr;

  for (int kc=0; kc<K; kc+=128){
    if (kc) __syncthreads();
    // ---- stage A ----
    if (AM==0){
      const ushortx* Ab = (const ushortx*)Asrc + z*strideA;
      const float4* ag = (const float4*)(Ab + (long long)row*K + kc + cs);
      #pragma unroll
      for (int u=0;u<4;u++) *(float4*)&At[sr][cs+u*8] = ag[u];
    } else if (AM==3){
      const float* Af_ = (const float*)Asrc;
      const float4* ar = (const float4*)(Af_ + (long long)row*128 + cs);
      #pragma unroll
      for (int u=0;u<4;u++){
        float4 a = ar[2*u], b = ar[2*u+1];
        U8 pk;
        pk.u[0]=f2b(a.x); pk.u[1]=f2b(a.y); pk.u[2]=f2b(a.z); pk.u[3]=f2b(a.w);
        pk.u[4]=f2b(b.x); pk.u[5]=f2b(b.y); pk.u[6]=f2b(b.z); pk.u[7]=f2b(b.w);
        *(float4*)&At[sr][cs+u*8] = pk.v;
      }
    } else if (AM==2){
      const float* hp = (const float*)Asrc;
      const float4* xr = (const float4*)(hp + (long long)row*512 + kc + cs);
      const float4* yr = (const float4*)(hp + (long long)row*512 + 256 + kc + cs);
      #pragma unroll
      for (int u=0;u<4;u++){
        float4 xa = xr[2*u], xb = xr[2*u+1];
        float4 ya = yr[2*u], yb = yr[2*u+1];
        U8 pk;
        pk.u[0]=f2b(xa.x*sigm(xa.x)*ya.x); pk.u[1]=f2b(xa.y*sigm(xa.y)*ya.y);
        pk.u[2]=f2b(xa.z*sigm(xa.z)*ya.z); pk.u[3]=f2b(xa.w*sigm(xa.w)*ya.w);
        pk.u[4]=f2b(xb.x*sigm(xb.x)*yb.x); pk.u[5]=f2b(xb.y*sigm(xb.y)*yb.y);
        pk.u[6]=f2b(xb.z*sigm(xb.z)*yb.z); pk.u[7]=f2b(xb.w*sigm(xb.w)*yb.w);
        *(float4*)&At[sr][cs+u*8] = pk.v;
      }
    } else { // AM==1 or AM==4: LN staging, K=128
      const float* arow = (AM==4) ? ((const float*)Asrc + (long long)row*128)
                                  : ((const float*)Asrc + (long long)row*128);
      float x[32]; float s=0.f, sq=0.f;
      const float4* ar = (const float4*)(arow + cs);
      #pragma unroll
      for (int u=0;u<8;u++){
        float4 t = ar[u];
        x[4*u]=t.x; x[4*u+1]=t.y; x[4*u+2]=t.z; x[4*u+3]=t.w;
        s += t.x+t.y+t.z+t.w;
        sq += t.x*t.x+t.y*t.y+t.z*t.z+t.w*t.w;
      }
      s += __shfl_xor(s,1); s += __shfl_xor(s,2);
      sq += __shfl_xor(sq,1); sq += __shfl_xor(sq,2);
      float mu = s*(1.f/128.f), var = sq*(1.f/128.f)-mu*mu;
      float rs = rsqrtf(var + 1e-5f);
      if (AM==1){
        const float* sp = p1 + (long long)(row & (NATOM-1))*384;
        const float4* gr = (const float4*)(sp + cs);
        const float4* hr = (const float4*)(sp + 128 + cs);
        #pragma unroll
        for (int u=0;u<4;u++){
          float4 ga = gr[2*u], gb = gr[2*u+1];
          float4 ha = hr[2*u], hb = hr[2*u+1];
          U8 pk;
          pk.u[0]=f2b(sigm(ga.x)*((x[8*u  ]-mu)*rs)+ha.x);
          pk.u[1]=f2b(sigm(ga.y)*((x[8*u+1]-mu)*rs)+ha.y);
          pk.u[2]=f2b(sigm(ga.z)*((x[8*u+2]-mu)*rs)+ha.z);
          pk.u[3]=f2b(sigm(ga.w)*((x[8*u+3]-mu)*rs)+ha.w);
          pk.u[4]=f2b(sigm(gb.x)*((x[8*u+4]-mu)*rs)+hb.x);
          pk.u[5]=f2b(sigm(gb.y)*((x[8*u+5]-mu)*rs)+hb.y);
          pk.u[6]=f2b(sigm(gb.z)*((x[8*u+6]-mu)*rs)+hb.z);
          pk.u[7]=f2b(sigm(gb.w)*((x[8*u+7]-mu)*rs)+hb.w);
          *(float4*)&At[sr][cs+u*8] = pk.v;
        }
      } else { // AM==4
        int iw = z>>1, tw = z&1;
        const float* w = (tw?p3:p1) + iw*128;
        const float* b = (tw?p4:p2) + iw*128;
        const float4* wrp = (const float4*)(w + cs);
        const float4* brp = (const float4*)(b + cs);
        #pragma unroll
        for (int u=0;u<4;u++){
          float4 wa = wrp[2*u], wb = wrp[2*u+1];
          float4 ba = brp[2*u], bb = brp[2*u+1];
          U8 pk;
          pk.u[0]=f2b((x[8*u  ]-mu)*rs*wa.x+ba.x);
          pk.u[1]=f2b((x[8*u+1]-mu)*rs*wa.y+ba.y);
          pk.u[2]=f2b((x[8*u+2]-mu)*rs*wa.z+ba.z);
          pk.u[3]=f2b((x[8*u+3]-mu)*rs*wa.w+ba.w);
          pk.u[4]=f2b((x[8*u+4]-mu)*rs*wb.x+bb.x);
          pk.u[5]=f2b((x[8*u+5]-mu)*rs*wb.y+bb.y);
          pk.u[6]=f2b((x[8*u+6]-mu)*rs*wb.z+bb.z);
          pk.u[7]=f2b((x[8*u+7]-mu)*rs*wb.w+bb.w);
          *(float4*)&At[sr][cs+u*8] = pk.v;
        }
      }
    }
    // ---- stage B ----
    {
      const float4* bg = (const float4*)(B + (long long)(colBase+sr)*K + kc + cs);
      #pragma unroll
      for (int u=0;u<4;u++) *(float4*)&Bt[sr][cs+u*8] = bg[u];
    }
    __syncthreads();
    #pragma unroll
    for (int ks=0; ks<4; ks++){
      bf16x8 a0 = *(const bf16x8*)&At[wr+lr][ks*32+lk];
      bf16x8 a1 = *(const bf16x8*)&At[wr+16+lr][ks*32+lk];
      bf16x8 b0 = *(const bf16x8*)&Bt[wc+lr][ks*32+lk];
      bf16x8 b1 = *(const bf16x8*)&Bt[wc+16+lr][ks*32+lk];
      acc[0][0] = __builtin_amdgcn_mfma_f32_16x16x32_bf16(a0,b0,acc[0][0],0,0,0);
      acc[0][1] = __builtin_amdgcn_mfma_f32_16x16x32_bf16(a0,b1,acc[0][1],0,0,0);
      acc[1][0] = __builtin_amdgcn_mfma_f32_16x16x32_bf16(a1,b0,acc[1][0],0,0,0);
      acc[1][1] = __builtin_amdgcn_mfma_f32_16x16x32_bf16(a1,b1,acc[1][1],0,0,0);
    }
  }
  int crow0 = rowBase + wr + (lane>>4)*4;
  int ccol0 = colBase + wc + lr;
  #pragma unroll
  for (int i=0;i<2;i++){
    #pragma unroll
    for (int j=0;j<2;j++){
      int col = ccol0 + j*16;
      float bv = bias ? bias[col] : 0.f;
      #pragma unroll
      for (int rr=0; rr<4; rr++){
        int rrow = crow0 + i*16 + rr;
        float v = acc[i][j][rr] + bv;
        long long ci = (long long)rrow*N + col;
        if (mode==1) C[ci] = fmaxf(v, 0.f);
        else if (mode==2){
          int n = rrow & (NATOM-1);
          C[ci] += sigm(gate[(long long)n*gate_ld + gate_coloff + col]) * v;
        } else C[ci] = v;
      }
    }
  }
}

__global__ __launch_bounds__(128) void tokagg_kernel(const int* __restrict__ tok_idx,
    const float* __restrict__ qtok, float* __restrict__ out)
{
  int t = blockIdx.x;
  int lo=0, hi=NATOM;
  while (lo<hi){ int mid=(lo+hi)>>1; if (tok_idx[mid] < t) lo=mid+1; else hi=mid; }
  int start = lo;
  lo = start; hi = NATOM;
  while (lo<hi){ int mid=(lo+hi)>>1; if (tok_idx[mid] <= t) lo=mid+1; else hi=mid; }
  int end = lo;
  int cnt = end - start;
  float inv = 1.0f / (float)(cnt>0 ? cnt : 1);
  for (int s=0; s<SD; s++)
    for (int c=threadIdx.x; c<CTD; c+=128){
      float acc = 0.f;
      for (int n=start; n<end; n++) acc += qtok[((long long)(s*NATOM+n))*CTD + c];
      out[(long long)(s*TT + t)*CTD + c] = acc*inv;
    }
}

extern "C" void kernel_launch(void* const* d_in, const int* in_sizes, int n_in,
                              void* d_out, int out_size, void* d_ws, size_t ws_size,
                              hipStream_t stream)
{
  const float* atom_single = (const float*)d_in[0];
  const float* atom_proj   = (const float*)d_in[1];
  const float* atom_pair   = (const float*)d_in[2];
  const float* mask        = (const float*)d_in[3];
  const int*   tok_idx     = (const int*)  d_in[4];
  const float* aln_s_w     = (const float*)d_in[5];
  const float* aln_s_b     = (const float*)d_in[6];
  const float* pair_ln_w   = (const float*)d_in[14];
  const float* pair_ln_b   = (const float*)d_in[15];
  const float* pair_w      = (const float*)d_in[16];
  const float* t_aln_s_w   = (const float*)d_in[21];
  const float* t_aln_s_b   = (const float*)d_in[22];

  char* wsb = (char*)d_ws;
  ushortx* W3T    = (ushortx*)(wsb+OFFB_W3T);
  float*   B3     = (float*)  (wsb+OFFB_B3);
  ushortx* WQKVGT = (ushortx*)(wsb+OFFB_WQKVGT);
  float*   BQ     = (float*)  (wsb+OFFB_BQ);
  ushortx* WOUTT  = (ushortx*)(wsb+OFFB_WOUTT);
  ushortx* WABT   = (ushortx*)(wsb+OFFB_WABT);
  ushortx* WTOUTT = (ushortx*)(wsb+OFFB_WTOUTT);
  ushortx* WTOKT  = (ushortx*)(wsb+OFFB_WTOKT);
  ushortx* A1     = (ushortx*)(wsb+OFFB_A1);
  float*   SNP    = (float*)  (wsb+OFFB_SNP);
  float*   Af     = (float*)  (wsb+OFFB_A);
  float*   QKVG   = (float*)  (wsb+OFFB_QKVG);
  float*   ZB     = (float*)  (wsb+OFFB_ZB);
  float*   QTOK   = (float*)  (wsb+OFFB_QTOK);

  WPtrs P;
  P.aln_gate_w=(const float*)d_in[7];  P.aln_gate_b=(const float*)d_in[8];  P.aln_shift_w=(const float*)d_in[9];
  P.og_w=(const float*)d_in[19]; P.og_b=(const float*)d_in[20];
  P.t_aln_gate_w=(const float*)d_in[23]; P.t_aln_gate_b=(const float*)d_in[24]; P.t_aln_shift_w=(const float*)d_in[25];
  P.t_og_w=(const float*)d_in[29]; P.t_og_b=(const float*)d_in[30];
  P.q_w=(const float*)d_in[10]; P.q_b=(const float*)d_in[11]; P.k_w=(const float*)d_in[12];
  P.v_w=(const float*)d_in[13]; P.gate_w=(const float*)d_in[17]; P.out_w=(const float*)d_in[18];
  P.t_a_w=(const float*)d_in[26]; P.t_b_w=(const float*)d_in[27]; P.t_out_w=(const float*)d_in[28];
  P.tok_w=(const float*)d_in[31];

  pack_kernel<<<3471,256,0,stream>>>(P, wsb);
  zb_kernel<<<1024,256,0,stream>>>(atom_pair, pair_ln_w, pair_ln_b, pair_w, ZB);
  // snp[which] = (LN(atom_proj)*w_which+b_which) @ W3[which]^T + b3[which]
  gemm_f<4><<<dim3(6,32,6),256,0,stream>>>(atom_proj, 0, W3T, 49152ll,
      B3, 384ll, SNP, 786432ll, NATOM, 384, 128, 0, nullptr, 0, 0,
      aln_s_w, aln_s_b, t_aln_s_w, t_aln_s_b);
  copy_f<<<2048,256,0,stream>>>(atom_single, Af, MR*CD);

  for (int i=0;i<NBI;i++){
    const float* snpA = SNP + (long long)(2*i)*786432;
    const float* snpT = SNP + (long long)(2*i+1)*786432;
    // qkvg = modln(a) @ [q|k|v|gate] (+[q_b|0|0|0])
    gemm_f<1><<<dim3(8,64,1),256,0,stream>>>(Af, 0, WQKVGT + (long long)i*65536, 0,
        BQ + (long long)i*512, 0, QKVG, 0, MR, 512, 128, 0, nullptr, 0, 0,
        snpA, nullptr, nullptr, nullptr);
    attn_kernel<<<dim3(64,8,2),256,0,stream>>>(QKVG, ZB + (long long)i*2097152, mask, A1);
    // a += sigmoid(og_pre) * (og @ out_w)
    gemm_f<0><<<dim3(2,64,1),256,0,stream>>>(A1, 0, WOUTT + (long long)i*16384, 0,
        nullptr, 0, Af, 0, MR, 128, 128, 2, snpA, 384, 256,
        nullptr, nullptr, nullptr, nullptr);
    // hidden_pre = modln(a) @ [t_a|t_b]
    gemm_f<1><<<dim3(8,64,1),256,0,stream>>>(Af, 0, WABT + (long long)i*65536, 0,
        nullptr, 0, QKVG, 0, MR, 512, 128, 0, nullptr, 0, 0,
        snpT, nullptr, nullptr, nullptr);
    // a += sigmoid(t_og_pre) * (silu(h_a)*h_b @ t_out_w)
    gemm_f<2><<<dim3(2,64,1),256,0,stream>>>(QKVG, 0, WTOUTT + (long long)i*32768, 0,
        nullptr, 0, Af, 0, MR, 128, 256, 2, snpT, 384, 256,
        nullptr, nullptr, nullptr, nullptr);
  }
  // q_tok = relu(a @ tok_w)
  gemm_f<3><<<dim3(6,64,1),256,0,stream>>>(Af, 0, WTOKT, 0, nullptr, 0,
      QTOK, 0, MR, CTD, 128, 1, nullptr, 0, 0,
      nullptr, nullptr, nullptr, nullptr);
  tokagg_kernel<<<TT,128,0,stream>>>(tok_idx, QTOK, (float*)d_out);
}